// Round 15
// baseline (1136.439 us; speedup 1.0000x reference)
//
#include <hip/hip_runtime.h>
#include <math.h>

#define Bb 64
#define Ss 512
#define Hh 256
#define Vv 32000
#define BS (Bb*Ss)      // 32768
#define NSTEPS 10

typedef __attribute__((ext_vector_type(8))) short bf16x8;   // 8 bf16 = 4 VGPR
typedef __attribute__((ext_vector_type(4))) float f32x4;    // MFMA C/D frag
typedef unsigned short u16;

#define MFMA(a,b,c) __builtin_amdgcn_mfma_f32_16x16x32_bf16((a),(b),(c),0,0,0)

__device__ __forceinline__ u16 f2bf(float f) {              // RNE
    unsigned u = __float_as_uint(f);
    u += 0x7fffu + ((u >> 16) & 1u);
    return (u16)(u >> 16);
}
__device__ __forceinline__ float bf2f(u16 h) {
    return __uint_as_float(((unsigned)h) << 16);
}
// physical Bbig column for (hcol j, gate g): fn-of-wave == gate
__device__ __forceinline__ int nmap(int j, int g) {
    return ((j >> 4) << 6) | (g << 4) | (j & 15);
}
#define GLL(src, dst) __builtin_amdgcn_global_load_lds( \
    (const __attribute__((address_space(1))) void*)(src), \
    (__attribute__((address_space(3))) void*)(dst), 16, 0, 0)

// ---------------------------------------------------------------------------
// prep: Bbig[nmap(j,g)][seg*256+k] = sum_k' W_edge[segmap][k][k'] * W_ih[g*256+j][k']
//       (+ W_hh[g*256+j][k] for seg==0 (self) and g in {r,z})
// seg order: 0=self(We[2]), 1=fwd h[s-1] (We[0]), 2=bwd h[s+1] (We[1])
// ---------------------------------------------------------------------------
__global__ __launch_bounds__(256)
void k_prep_big(const float* __restrict__ We, const float* __restrict__ Wih,
                const float* __restrict__ Whh, u16* __restrict__ Bbig) {
    __shared__ u16 Aps[64 * 32];
    __shared__ u16 Bps[64 * 32];
    const int p = blockIdx.y, seg = p / 3, g = p % 3;
    const int segmap0 = (seg == 0) ? 2 : (seg == 1 ? 0 : 1);
    const float* Wseg = We + segmap0 * 65536;
    const int kt = (blockIdx.x >> 2) * 64, jt = (blockIdx.x & 3) * 64;
    const int t = threadIdx.x;
    const int lane = t & 63, wid = t >> 6;
    const int wy = (wid >> 1) * 32, wx = (wid & 1) * 32;
    const int lr = lane & 15, hi = lane >> 4;

    f32x4 acc[2][2];
    #pragma unroll
    for (int a = 0; a < 2; ++a)
        #pragma unroll
        for (int b = 0; b < 2; ++b) acc[a][b] = 0.0f;

    for (int ks = 0; ks < 8; ++ks) {
        const int k0 = ks * 32;
        {
            int r = t >> 2, kc = t & 3;
            const float* sa = Wseg + (kt + r) * 256 + k0 + kc * 8;
            float4 a0 = *(const float4*)sa, a1 = *(const float4*)(sa + 4);
            bf16x8 va;
            va[0]=(short)f2bf(a0.x); va[1]=(short)f2bf(a0.y); va[2]=(short)f2bf(a0.z); va[3]=(short)f2bf(a0.w);
            va[4]=(short)f2bf(a1.x); va[5]=(short)f2bf(a1.y); va[6]=(short)f2bf(a1.z); va[7]=(short)f2bf(a1.w);
            ((bf16x8*)Aps)[r * 4 + (kc ^ (r & 3))] = va;
            const float* sb = Wih + (g * 256 + jt + r) * 256 + k0 + kc * 8;
            float4 b0 = *(const float4*)sb, b1 = *(const float4*)(sb + 4);
            bf16x8 vb;
            vb[0]=(short)f2bf(b0.x); vb[1]=(short)f2bf(b0.y); vb[2]=(short)f2bf(b0.z); vb[3]=(short)f2bf(b0.w);
            vb[4]=(short)f2bf(b1.x); vb[5]=(short)f2bf(b1.y); vb[6]=(short)f2bf(b1.z); vb[7]=(short)f2bf(b1.w);
            ((bf16x8*)Bps)[r * 4 + (kc ^ (r & 3))] = vb;
        }
        __syncthreads();
        bf16x8 af[2], bfv[2];
        #pragma unroll
        for (int f = 0; f < 2; ++f) {
            int ra = wy + f * 16 + lr;
            af[f]  = ((const bf16x8*)Aps)[ra * 4 + (hi ^ (ra & 3))];
            int rb = wx + f * 16 + lr;
            bfv[f] = ((const bf16x8*)Bps)[rb * 4 + (hi ^ (rb & 3))];
        }
        #pragma unroll
        for (int fm = 0; fm < 2; ++fm)
            #pragma unroll
            for (int fn = 0; fn < 2; ++fn)
                acc[fm][fn] = MFMA(af[fm], bfv[fn], acc[fm][fn]);
        __syncthreads();
    }
    #pragma unroll
    for (int fm = 0; fm < 2; ++fm)
        #pragma unroll
        for (int fn = 0; fn < 2; ++fn) {
            int kbase = kt + wy + fm * 16 + hi * 4;
            int j     = jt + wx + fn * 16 + lr;
            float4 wv = make_float4(0.f, 0.f, 0.f, 0.f);
            if (seg == 0 && g < 2)
                wv = *(const float4*)(Whh + (g * 256 + j) * 256 + kbase);
            ushort4 o;
            o.x = f2bf(acc[fm][fn][0] + wv.x);
            o.y = f2bf(acc[fm][fn][1] + wv.y);
            o.z = f2bf(acc[fm][fn][2] + wv.z);
            o.w = f2bf(acc[fm][fn][3] + wv.w);
            *(ushort4*)(Bbig + (size_t)nmap(j, g) * 768 + seg * 256 + kbase) = o;
        }
}

// gate-3 (HN) rows of Bbig: seg0 = Whn^T, seg1/2 = 0
__global__ __launch_bounds__(256)
void k_prep_hn(const float* __restrict__ Whh, u16* __restrict__ Bbig) {
    int j = blockIdx.x / 3;
    int k = (blockIdx.x % 3) * 256 + threadIdx.x;
    Bbig[(size_t)nmap(j, 3) * 768 + k] =
        (k < 256) ? f2bf(Whh[(512 + j) * 256 + k]) : (u16)0;
}

// bias table [3 classes][1024 physical cols]; class 0: s==0, 1: interior, 2: s==S-1
__global__ __launch_bounds__(256)
void k_prep_bias(const float* __restrict__ Wih, const float* __restrict__ b_edge,
                 const float* __restrict__ b_ih, const float* __restrict__ b_hh,
                 float* __restrict__ bias) {
    int id = blockIdx.x * 256 + threadIdx.x;       // 3072
    int c = id >> 10, n = id & 1023;
    int g = (n >> 4) & 3;
    int j = ((n >> 6) << 4) | (n & 15);
    float a;
    if (g == 3) {
        a = b_hh[512 + j];
    } else {
        a = b_ih[g * 256 + j] + (g < 2 ? b_hh[g * 256 + j] : 0.f);
        const float* wrow = Wih + (g * 256 + j) * 256;
        for (int k = 0; k < 256; ++k) {
            float eb = b_edge[512 + k] + (c != 0 ? b_edge[k] : 0.f)
                     + (c != 2 ? b_edge[256 + k] : 0.f);
            a += eb * wrow[k];
        }
    }
    bias[c * 1024 + n] = a;
}

// ---------------------------------------------------------------------------
// h0 = emb[x] -> bf16
// ---------------------------------------------------------------------------
__global__ __launch_bounds__(256)
void k_embed(const int* __restrict__ x, const float* __restrict__ emb,
             u16* __restrict__ h) {
    int idx = blockIdx.x * 256 + threadIdx.x;       // 8-elem chunk id
    int row = idx >> 5, c8 = idx & 31;
    long long tok = x[row];
    const float4* e = reinterpret_cast<const float4*>(emb + tok * Hh + c8 * 8);
    float4 a = e[0], b = e[1];
    bf16x8 v;
    v[0]=(short)f2bf(a.x); v[1]=(short)f2bf(a.y); v[2]=(short)f2bf(a.z); v[3]=(short)f2bf(a.w);
    v[4]=(short)f2bf(b.x); v[5]=(short)f2bf(b.y); v[6]=(short)f2bf(b.z); v[7]=(short)f2bf(b.w);
    ((bf16x8*)h)[idx] = v;
}

// ---------------------------------------------------------------------------
// Fused step v11: GEMM M=32768 x N=1024 x K=768 + lane-parallel GRU epilogue.
// = r4 geometry (BM=128, BN=256, BK=64, 512 thr, 8 waves 2x4, wave tile
//   64x64, single-buffer stage->sync->compute->sync, ~50 KB LDS -> 2-3
//   blocks/CU for cross-block overlap of the drain)
// + r13 A-reuse (A[k0] staged ONCE per k0 into [128][64] + 2 halo rows;
//   the 3 segs read it with row shift 0/-1/+1; boundary edge lanes use
//   halo chunks or a zero predicate)
// + HN-zero staging skip (segs 1,2: waves 6,7 — the gate-3 columns —
//   skip B staging entirely; COMPUTE never reads those chunks).
// ---------------------------------------------------------------------------
__global__ __launch_bounds__(512, 4)
void k_step(const u16* __restrict__ hin, const u16* __restrict__ Bbig,
            const float* __restrict__ bias, u16* __restrict__ hout) {
    // A: 128 rows x 8 chunks (1024) + halo GLL spans (1024..1087, 1088..1151)
    __shared__ __attribute__((aligned(16))) u16 As[1152 * 8];   // 18 KB
    __shared__ __attribute__((aligned(16))) u16 Bs[256 * 64];   // 32 KB
    const int t = threadIdx.x;
    const int lane = t & 63, wid = t >> 6;
    // XCD-aware bijective swizzle: 1024 blocks = 8 XCDs x 128
    const int swz = (blockIdx.x & 7) * 128 + (blockIdx.x >> 3);
    const int rowBlk = (swz >> 2) * 128;
    const int colBlk = (swz & 3) * 256;
    const int wy = wid >> 2, wx = wid & 3;          // 2 x 4 waves, tile 64x64
    const int lr = lane & 15, hi = lane >> 4;
    const int s0 = rowBlk & (Ss - 1);               // 0,128,256,384

    const int q   = t >> 3;                         // 0..63
    const int off = ((t & 7) ^ (q & 7)) << 3;       // pre-swizzled elem offset

    // staging sources
    const u16* pA[2];
    pA[0] = hin + (size_t)(rowBlk + q) * Hh + off;
    pA[1] = hin + (size_t)(rowBlk + 64 + q) * Hh + off;
    const u16* pB[4];
    #pragma unroll
    for (int j = 0; j < 4; ++j)
        pB[j] = Bbig + (size_t)(colBlk + j * 64 + q) * 768 + off;
    // halo rows (clamped when nonexistent; zero predicate applied at read)
    const int haloLoRow = (s0 > 0)          ? rowBlk - 1   : rowBlk;
    const int haloHiRow = (s0 < Ss - 128)   ? rowBlk + 128 : rowBlk;
    const u16* haloLo = hin + (size_t)haloLoRow * Hh + lane * 8;
    const u16* haloHi = hin + (size_t)haloHiRow * Hh + lane * 8;

    f32x4 acc[4][4];
    #pragma unroll
    for (int a = 0; a < 4; ++a)
        #pragma unroll
        for (int b = 0; b < 4; ++b) acc[a][b] = 0.0f;

    #pragma unroll
    for (int kq = 0; kq < 4; ++kq) {
        const int ko = kq * 64;
        // ---- STAGE_A: 128 rows once per kq (2 GLL/thread) + 2 halo GLLs
        GLL(pA[0] + ko, As + (size_t)(wid * 64) * 8);
        GLL(pA[1] + ko, As + (size_t)(512 + wid * 64) * 8);
        if (wid == 0) GLL(haloLo + ko, As + 1024 * 8);
        if (wid == 1) GLL(haloHi + ko, As + 1088 * 8);

        #pragma unroll
        for (int seg = 0; seg < 3; ++seg) {
            // ---- STAGE_B (waves 6,7 = gate-3 cols: skip when seg != 0)
            const int o = seg * 256 + ko;
            if (seg == 0 || wid < 6) {
                #pragma unroll
                for (int j = 0; j < 4; ++j)
                    GLL(pB[j] + o, Bs + (size_t)(j * 512 + wid * 64) * 8);
            }
            __syncthreads();                        // drain GLL + barrier
            // ---- COMPUTE
            const int d = (seg == 0) ? 0 : (seg == 1 ? -1 : 1);
            #pragma unroll
            for (int kk = 0; kk < 2; ++kk) {
                const int kc = kk * 4 + hi;         // k-chunk 0..7
                bf16x8 bfv[4];
                #pragma unroll
                for (int f = 0; f < 4; ++f) {
                    if (seg != 0 && f == 3) continue;   // HN: segs 1,2 zero
                    int rb = wx * 64 + f * 16 + lr;
                    bfv[f] = ((const bf16x8*)Bs)[rb * 8 + (kc ^ (rb & 7))];
                }
                bf16x8 af[4];
                #pragma unroll
                for (int f = 0; f < 4; ++f) {
                    int rr = wy * 64 + f * 16 + lr + d;
                    bf16x8 av;
                    if (d < 0 && wy == 0 && f == 0) {
                        bool bd = (lr == 0);            // rr == -1
                        int idx = bd ? (1024 + kc) : (rr * 8 + (kc ^ (rr & 7)));
                        av = ((const bf16x8*)As)[idx];
                        if (bd && s0 == 0) { bf16x8 zz = 0; av = zz; }
                    } else if (d > 0 && wy == 1 && f == 3) {
                        bool bd = (lr == 15);           // rr == 128
                        int idx = bd ? (1088 + kc) : (rr * 8 + (kc ^ (rr & 7)));
                        av = ((const bf16x8*)As)[idx];
                        if (bd && s0 == Ss - 128) { bf16x8 zz = 0; av = zz; }
                    } else {
                        av = ((const bf16x8*)As)[rr * 8 + (kc ^ (rr & 7))];
                    }
                    af[f] = av;
                }
                __builtin_amdgcn_s_setprio(1);
                #pragma unroll
                for (int fm = 0; fm < 4; ++fm)
                    #pragma unroll
                    for (int fn = 0; fn < 4; ++fn)
                        if (seg == 0 || fn < 3)
                            acc[fm][fn] = MFMA(af[fm], bfv[fn], acc[fm][fn]);
                __builtin_amdgcn_s_setprio(0);
            }
            __syncthreads();                        // readers done before next stage
        }
    }

    // ---- lane-parallel GRU epilogue: fn == gate, lane owns (rows, one hcol)
    const int hq = (colBlk >> 2) + wx * 16;
    #pragma unroll
    for (int mf = 0; mf < 4; ++mf)
        #pragma unroll
        for (int i = 0; i < 4; ++i) {
            int row = rowBlk + wy * 64 + mf * 16 + hi * 4 + i;
            int s = row & (Ss - 1);
            int cls = (s == 0) ? 0 : ((s == Ss - 1) ? 2 : 1);
            const float* bp = bias + cls * 1024 + colBlk + wx * 64 + lr;
            float vr = acc[mf][0][i] + bp[0];
            float vz = acc[mf][1][i] + bp[16];
            float vn = acc[mf][2][i] + bp[32];
            float vh = acc[mf][3][i] + bp[48];
            float r = 1.f / (1.f + __expf(-vr));
            float z = 1.f / (1.f + __expf(-vz));
            float e = __expf(2.f * (vn + r * vh));
            float n = 1.f - 2.f / (e + 1.f);
            int hcol = hq + lr;
            float hold = bf2f(hin[(size_t)row * Hh + hcol]);
            hout[(size_t)row * Hh + hcol] = f2bf(n + z * (hold - n));
        }
}

// ---------------------------------------------------------------------------
// out = last @ out_w.T + out_b via MFMA. M=64, N=32000, K=256.
// ---------------------------------------------------------------------------
__global__ __launch_bounds__(256)
void k_out(const u16* __restrict__ h, const float* __restrict__ out_w,
           const float* __restrict__ out_b, float* __restrict__ out) {
    __shared__ u16 As[64 * 256];
    const int t = threadIdx.x;
    const int lane = t & 63, wid = t >> 6;
    const int colBlk = blockIdx.x * 128;
    const int wc = wid * 32;
    const int lr = lane & 15, hi = lane >> 4;

    #pragma unroll
    for (int i = 0; i < 8; ++i) {                   // 2048 chunks
        int c = t + i * 256;
        int r = c >> 5, kc = c & 31;
        bf16x8 v = *(const bf16x8*)(h + ((size_t)(r * Ss + (Ss - 1))) * Hh + kc * 8);
        ((bf16x8*)As)[r * 32 + (kc ^ (r & 7))] = v;
    }
    __syncthreads();

    f32x4 acc[4][2];
    #pragma unroll
    for (int a = 0; a < 4; ++a) { acc[a][0] = 0.0f; acc[a][1] = 0.0f; }

    #pragma unroll
    for (int ks = 0; ks < 8; ++ks) {
        bf16x8 af[4];
        #pragma unroll
        for (int f = 0; f < 4; ++f) {
            int ra = f * 16 + lr;
            af[f] = ((const bf16x8*)As)[ra * 32 + ((ks * 4 + hi) ^ (ra & 7))];
        }
        #pragma unroll
        for (int fn = 0; fn < 2; ++fn) {
            int n = colBlk + wc + fn * 16 + lr;
            const float* wp = out_w + (size_t)n * 256 + ks * 32 + hi * 8;
            float4 w0 = *(const float4*)wp, w1 = *(const float4*)(wp + 4);
            bf16x8 vb;
            vb[0]=(short)f2bf(w0.x); vb[1]=(short)f2bf(w0.y); vb[2]=(short)f2bf(w0.z); vb[3]=(short)f2bf(w0.w);
            vb[4]=(short)f2bf(w1.x); vb[5]=(short)f2bf(w1.y); vb[6]=(short)f2bf(w1.z); vb[7]=(short)f2bf(w1.w);
            #pragma unroll
            for (int fm = 0; fm < 4; ++fm)
                acc[fm][fn] = MFMA(af[fm], vb, acc[fm][fn]);
        }
    }
    #pragma unroll
    for (int fm = 0; fm < 4; ++fm)
        #pragma unroll
        for (int fn = 0; fn < 2; ++fn)
            #pragma unroll
            for (int i = 0; i < 4; ++i) {
                int row = fm * 16 + hi * 4 + i;
                int col = colBlk + wc + fn * 16 + lr;
                out[(size_t)row * Vv + col] = acc[fm][fn][i] + out_b[col];
            }
}

// ---------------------------------------------------------------------------
extern "C" void kernel_launch(void* const* d_in, const int* in_sizes, int n_in,
                              void* d_out, int out_size, void* d_ws, size_t ws_size,
                              hipStream_t stream) {
    const int*   x      = (const int*)  d_in[0];
    const float* emb    = (const float*)d_in[1];
    const float* W_edge = (const float*)d_in[2];
    const float* b_edge = (const float*)d_in[3];
    const float* W_ih   = (const float*)d_in[4];
    const float* W_hh   = (const float*)d_in[5];
    const float* b_ih   = (const float*)d_in[6];
    const float* b_hh   = (const float*)d_in[7];
    const float* out_w  = (const float*)d_in[8];
    const float* out_b  = (const float*)d_in[9];
    float* out = (float*)d_out;

    // ws: hA | hB | Bbig (bf16 1024x768) | bias (f32 3x1024)
    u16* hA   = (u16*)d_ws;
    u16* hB   = hA + (size_t)BS * Hh;
    u16* Bbig = hB + (size_t)BS * Hh;
    float* bias = (float*)(Bbig + (size_t)1024 * 768);

    k_prep_big <<<dim3(16, 9), 256, 0, stream>>>(W_edge, W_ih, W_hh, Bbig);
    k_prep_hn  <<<768, 256, 0, stream>>>(W_hh, Bbig);
    k_prep_bias<<<12, 256, 0, stream>>>(W_ih, b_edge, b_ih, b_hh, bias);
    k_embed    <<<BS * Hh / 8 / 256, 256, 0, stream>>>(x, emb, hA);

    u16* cur = hA;
    u16* nxt = hB;
    for (int step = 0; step < NSTEPS; ++step) {
        k_step<<<1024, 512, 0, stream>>>(cur, Bbig, bias, nxt);
        u16* tmp = cur; cur = nxt; nxt = tmp;
    }
    k_out<<<Vv / 128, 256, 0, stream>>>(cur, out_w, out_b, out);
}

// Round 16
// 542.138 us; speedup vs baseline: 2.0962x; 2.0962x over previous
//
#include <hip/hip_runtime.h>
#include <math.h>

#define Bb 64
#define Ss 512
#define Hh 256
#define Vv 32000
#define BS (Bb*Ss)      // 32768
#define NSTEPS 10

typedef __attribute__((ext_vector_type(8))) short bf16x8;   // 8 bf16 = 4 VGPR
typedef __attribute__((ext_vector_type(4))) float f32x4;    // MFMA C/D frag
typedef unsigned short u16;

#define MFMA(a,b,c) __builtin_amdgcn_mfma_f32_16x16x32_bf16((a),(b),(c),0,0,0)

__device__ __forceinline__ u16 f2bf(float f) {              // RNE
    unsigned u = __float_as_uint(f);
    u += 0x7fffu + ((u >> 16) & 1u);
    return (u16)(u >> 16);
}
__device__ __forceinline__ float bf2f(u16 h) {
    return __uint_as_float(((unsigned)h) << 16);
}
// physical Bbig column for (hcol j, gate g): fn-of-wave == gate
__device__ __forceinline__ int nmap(int j, int g) {
    return ((j >> 4) << 6) | (g << 4) | (j & 15);
}
#define GLL(src, dst) __builtin_amdgcn_global_load_lds( \
    (const __attribute__((address_space(1))) void*)(src), \
    (__attribute__((address_space(3))) void*)(dst), 16, 0, 0)

// ---------------------------------------------------------------------------
// prep: Bbig[nmap(j,g)][seg*256+k] = sum_k' W_edge[segmap][k][k'] * W_ih[g*256+j][k']
//       (+ W_hh[g*256+j][k] for seg==0 (self) and g in {r,z})
// seg order: 0=self(We[2]), 1=fwd h[s-1] (We[0]), 2=bwd h[s+1] (We[1])
// ---------------------------------------------------------------------------
__global__ __launch_bounds__(256)
void k_prep_big(const float* __restrict__ We, const float* __restrict__ Wih,
                const float* __restrict__ Whh, u16* __restrict__ Bbig) {
    __shared__ u16 Aps[64 * 32];
    __shared__ u16 Bps[64 * 32];
    const int p = blockIdx.y, seg = p / 3, g = p % 3;
    const int segmap0 = (seg == 0) ? 2 : (seg == 1 ? 0 : 1);
    const float* Wseg = We + segmap0 * 65536;
    const int kt = (blockIdx.x >> 2) * 64, jt = (blockIdx.x & 3) * 64;
    const int t = threadIdx.x;
    const int lane = t & 63, wid = t >> 6;
    const int wy = (wid >> 1) * 32, wx = (wid & 1) * 32;
    const int lr = lane & 15, hi = lane >> 4;

    f32x4 acc[2][2];
    #pragma unroll
    for (int a = 0; a < 2; ++a)
        #pragma unroll
        for (int b = 0; b < 2; ++b) acc[a][b] = 0.0f;

    for (int ks = 0; ks < 8; ++ks) {
        const int k0 = ks * 32;
        {
            int r = t >> 2, kc = t & 3;
            const float* sa = Wseg + (kt + r) * 256 + k0 + kc * 8;
            float4 a0 = *(const float4*)sa, a1 = *(const float4*)(sa + 4);
            bf16x8 va;
            va[0]=(short)f2bf(a0.x); va[1]=(short)f2bf(a0.y); va[2]=(short)f2bf(a0.z); va[3]=(short)f2bf(a0.w);
            va[4]=(short)f2bf(a1.x); va[5]=(short)f2bf(a1.y); va[6]=(short)f2bf(a1.z); va[7]=(short)f2bf(a1.w);
            ((bf16x8*)Aps)[r * 4 + (kc ^ (r & 3))] = va;
            const float* sb = Wih + (g * 256 + jt + r) * 256 + k0 + kc * 8;
            float4 b0 = *(const float4*)sb, b1 = *(const float4*)(sb + 4);
            bf16x8 vb;
            vb[0]=(short)f2bf(b0.x); vb[1]=(short)f2bf(b0.y); vb[2]=(short)f2bf(b0.z); vb[3]=(short)f2bf(b0.w);
            vb[4]=(short)f2bf(b1.x); vb[5]=(short)f2bf(b1.y); vb[6]=(short)f2bf(b1.z); vb[7]=(short)f2bf(b1.w);
            ((bf16x8*)Bps)[r * 4 + (kc ^ (r & 3))] = vb;
        }
        __syncthreads();
        bf16x8 af[2], bfv[2];
        #pragma unroll
        for (int f = 0; f < 2; ++f) {
            int ra = wy + f * 16 + lr;
            af[f]  = ((const bf16x8*)Aps)[ra * 4 + (hi ^ (ra & 3))];
            int rb = wx + f * 16 + lr;
            bfv[f] = ((const bf16x8*)Bps)[rb * 4 + (hi ^ (rb & 3))];
        }
        #pragma unroll
        for (int fm = 0; fm < 2; ++fm)
            #pragma unroll
            for (int fn = 0; fn < 2; ++fn)
                acc[fm][fn] = MFMA(af[fm], bfv[fn], acc[fm][fn]);
        __syncthreads();
    }
    #pragma unroll
    for (int fm = 0; fm < 2; ++fm)
        #pragma unroll
        for (int fn = 0; fn < 2; ++fn) {
            int kbase = kt + wy + fm * 16 + hi * 4;
            int j     = jt + wx + fn * 16 + lr;
            float4 wv = make_float4(0.f, 0.f, 0.f, 0.f);
            if (seg == 0 && g < 2)
                wv = *(const float4*)(Whh + (g * 256 + j) * 256 + kbase);
            ushort4 o;
            o.x = f2bf(acc[fm][fn][0] + wv.x);
            o.y = f2bf(acc[fm][fn][1] + wv.y);
            o.z = f2bf(acc[fm][fn][2] + wv.z);
            o.w = f2bf(acc[fm][fn][3] + wv.w);
            *(ushort4*)(Bbig + (size_t)nmap(j, g) * 768 + seg * 256 + kbase) = o;
        }
}

// gate-3 (HN) rows of Bbig: seg0 = Whn^T, seg1/2 = 0
__global__ __launch_bounds__(256)
void k_prep_hn(const float* __restrict__ Whh, u16* __restrict__ Bbig) {
    int j = blockIdx.x / 3;
    int k = (blockIdx.x % 3) * 256 + threadIdx.x;
    Bbig[(size_t)nmap(j, 3) * 768 + k] =
        (k < 256) ? f2bf(Whh[(512 + j) * 256 + k]) : (u16)0;
}

// bias table [3 classes][1024 physical cols]; class 0: s==0, 1: interior, 2: s==S-1
__global__ __launch_bounds__(256)
void k_prep_bias(const float* __restrict__ Wih, const float* __restrict__ b_edge,
                 const float* __restrict__ b_ih, const float* __restrict__ b_hh,
                 float* __restrict__ bias) {
    int id = blockIdx.x * 256 + threadIdx.x;       // 3072
    int c = id >> 10, n = id & 1023;
    int g = (n >> 4) & 3;
    int j = ((n >> 6) << 4) | (n & 15);
    float a;
    if (g == 3) {
        a = b_hh[512 + j];
    } else {
        a = b_ih[g * 256 + j] + (g < 2 ? b_hh[g * 256 + j] : 0.f);
        const float* wrow = Wih + (g * 256 + j) * 256;
        for (int k = 0; k < 256; ++k) {
            float eb = b_edge[512 + k] + (c != 0 ? b_edge[k] : 0.f)
                     + (c != 2 ? b_edge[256 + k] : 0.f);
            a += eb * wrow[k];
        }
    }
    bias[c * 1024 + n] = a;
}

// ---------------------------------------------------------------------------
// h0 = emb[x] -> bf16
// ---------------------------------------------------------------------------
__global__ __launch_bounds__(256)
void k_embed(const int* __restrict__ x, const float* __restrict__ emb,
             u16* __restrict__ h) {
    int idx = blockIdx.x * 256 + threadIdx.x;       // 8-elem chunk id
    int row = idx >> 5, c8 = idx & 31;
    long long tok = x[row];
    const float4* e = reinterpret_cast<const float4*>(emb + tok * Hh + c8 * 8);
    float4 a = e[0], b = e[1];
    bf16x8 v;
    v[0]=(short)f2bf(a.x); v[1]=(short)f2bf(a.y); v[2]=(short)f2bf(a.z); v[3]=(short)f2bf(a.w);
    v[4]=(short)f2bf(b.x); v[5]=(short)f2bf(b.y); v[6]=(short)f2bf(b.z); v[7]=(short)f2bf(b.w);
    ((bf16x8*)h)[idx] = v;
}

// ---------------------------------------------------------------------------
// Fused step v12 = r13 (best measured: 57.2 us/step) + HN-staging skip.
// GEMM M=32768 x N=1024 x K=768 + lane-parallel GRU epilogue.
// 256x256 tile, BK=64, 8 waves 2x4, wave tile 128x64, GLL staging, one
// __syncthreads per interval, 0-conflict XOR swizzle, XCD swizzle.
// A-REUSE: k0-outer/seg-inner; A[k0] staged once per k0 ([256][64] + halo
// row), 3 segs read with row shift -1/0/+1 (edge lanes: halo or zero).
// NEW: gate-3 (HN) B columns are zero for segs 1,2 -> waves 6,7 skip B
// staging on those 8/12 intervals (wave-uniform; compute never reads them).
// ---------------------------------------------------------------------------
__global__ __launch_bounds__(512, 2)
void k_step(const u16* __restrict__ hin, const u16* __restrict__ Bbig,
            const float* __restrict__ bias, u16* __restrict__ hout) {
    __shared__ __attribute__((aligned(16))) u16 As[2][256 * 64 + 512]; // 66 KB
    __shared__ __attribute__((aligned(16))) u16 Bs[2][2][128 * 64];    // 64 KB
    const int t = threadIdx.x;
    const int lane = t & 63, wid = t >> 6;
    // XCD-aware bijective swizzle: 512 blocks = 8 XCDs x 64
    const int swz = (blockIdx.x & 7) * 64 + (blockIdx.x >> 3);
    const int rowBlk = (swz >> 2) * 256;
    const int colBlk = (swz & 3) * 256;
    const int wy = wid >> 2, wx = wid & 3;          // 2 x 4 waves, tile 128x64
    const int lr = lane & 15, hi = lane >> 4;
    const int s0 = rowBlk & (Ss - 1);               // 0 or 256

    const int q   = t >> 3;                         // 0..63
    const int off = ((t & 7) ^ (q & 7)) << 3;       // pre-swizzled elem offset

    // staging sources (rows h*128+i*64+q); halo row: the one that exists
    const u16* pA[4];
    const u16* pB[4];
    #pragma unroll
    for (int j = 0; j < 4; ++j) {
        pA[j] = hin  + (size_t)(rowBlk + j * 64 + q) * Hh  + off;
        pB[j] = Bbig + (size_t)(colBlk + j * 64 + q) * 768 + off;
    }
    const u16* haloSrc = hin
        + (size_t)(s0 == 0 ? rowBlk + 256 : rowBlk - 1) * Hh + lane * 8;

    f32x4 acc[8][4];
    #pragma unroll
    for (int a = 0; a < 8; ++a)
        #pragma unroll
        for (int b = 0; b < 4; ++b) acc[a][b] = 0.0f;

    // stage A[k0=kqn*64] into A-buf kqn&1 (4 GLL + 1 halo GLL by wave 0)
    auto STAGE_A = [&](int kqn) {
        u16* aD = (u16*)As[kqn & 1];
        const int o = kqn * 64;
        #pragma unroll
        for (int h = 0; h < 2; ++h)
            #pragma unroll
            for (int i = 0; i < 2; ++i)
                GLL(pA[h * 2 + i] + o, aD + h * 8192 + (i * 512 + wid * 64) * 8);
        if (wid == 0) GLL(haloSrc + o, aD + 16384);   // pad absorbs lanes 8-63
    };
    // stage B tile for interval itn=(kqn,segn) into B-buf itn&1 (4 GLL).
    // Gate-3 rows (q>=48 <=> wid 6,7) are zero for segs 1,2 -> skip staging.
    auto STAGE_B = [&](int itn) {
        const int kqn = itn / 3, segn = itn % 3;
        if (segn != 0 && wid >= 6) return;          // wave-uniform skip
        u16* bD = (u16*)Bs[itn & 1];
        const int o = segn * 256 + kqn * 64;
        #pragma unroll
        for (int h = 0; h < 2; ++h)
            #pragma unroll
            for (int i = 0; i < 2; ++i)
                GLL(pB[h * 2 + i] + o, bD + h * 8192 + (i * 512 + wid * 64) * 8);
    };
    // compute interval (kq, seg): A rows shifted by d at read time
    auto COMPUTE = [&](int kq, int seg) {
        const bf16x8* aB = (const bf16x8*)As[kq & 1];
        const bf16x8* bB = (const bf16x8*)Bs[(kq * 3 + seg) & 1];
        const int d = (seg == 0) ? 0 : (seg == 1 ? -1 : 1);
        #pragma unroll
        for (int kk = 0; kk < 2; ++kk) {
            bf16x8 bfv[4];
            #pragma unroll
            for (int f = 0; f < 4; ++f) {
                if (seg != 0 && f == 3) continue;   // HN gate: segs 1,2 zero
                int rwb = (wx & 1) * 64 + f * 16 + lr;
                bfv[f] = bB[(wx >> 1) * 1024 + rwb * 8 + ((kk * 4 + hi) ^ (lr & 7))];
            }
            #pragma unroll
            for (int mh = 0; mh < 2; ++mh) {
                bf16x8 af[4];
                #pragma unroll
                for (int f = 0; f < 4; ++f) {
                    int rr  = wy * 128 + mh * 64 + f * 16 + lr + d;
                    int idx = rr * 8 + ((kk * 4 + hi) ^ (rr & 7));
                    bf16x8 av;
                    if (d < 0 && mh == 0 && f == 0) {
                        // edge: rr==-1 for (wy==0, lr==0) -> halo or zero
                        bool bd = (wy == 0) && (lr == 0);
                        av = aB[bd ? (2048 + kk * 4 + hi) : idx];
                        if (bd && s0 == 0) { bf16x8 zz = 0; av = zz; }
                    } else if (d > 0 && mh == 1 && f == 3) {
                        // edge: rr==256 for (wy==1, lr==15) -> idx lands on
                        // halo pad naturally (256*8 + c); zero if halo is top
                        bool bd = (wy == 1) && (lr == 15);
                        av = aB[idx];
                        if (bd && s0 != 0) { bf16x8 zz = 0; av = zz; }
                    } else {
                        av = aB[idx];
                    }
                    af[f] = av;
                }
                __builtin_amdgcn_s_setprio(1);
                #pragma unroll
                for (int fm = 0; fm < 4; ++fm)
                    #pragma unroll
                    for (int fn = 0; fn < 4; ++fn)
                        if (seg == 0 || fn < 3)
                            acc[mh * 4 + fm][fn] =
                                MFMA(af[fm], bfv[fn], acc[mh * 4 + fm][fn]);
                __builtin_amdgcn_s_setprio(0);
            }
        }
    };

    // ---- prologue
    STAGE_A(0);
    STAGE_B(0);
    __syncthreads();
    // ---- main loop: 4 k0-blocks x 3 segs = 12 intervals
    #pragma unroll
    for (int kq = 0; kq < 4; ++kq)
        #pragma unroll
        for (int seg = 0; seg < 3; ++seg) {
            const int it = kq * 3 + seg;
            if (it < 11) STAGE_B(it + 1);
            if (seg == 0 && kq < 3) STAGE_A(kq + 1);
            COMPUTE(kq, seg);
            __syncthreads();
        }

    // ---- lane-parallel GRU epilogue: fn == gate, lane owns (rows, one hcol)
    const int hq = (colBlk >> 2) + wx * 16;
    #pragma unroll
    for (int mf = 0; mf < 8; ++mf)
        #pragma unroll
        for (int i = 0; i < 4; ++i) {
            int row = rowBlk + wy * 128 + mf * 16 + hi * 4 + i;
            int s = row & (Ss - 1);
            int cls = (s == 0) ? 0 : ((s == Ss - 1) ? 2 : 1);
            const float* bp = bias + cls * 1024 + colBlk + wx * 64 + lr;
            float vr = acc[mf][0][i] + bp[0];
            float vz = acc[mf][1][i] + bp[16];
            float vn = acc[mf][2][i] + bp[32];
            float vh = acc[mf][3][i] + bp[48];
            float r = 1.f / (1.f + __expf(-vr));
            float z = 1.f / (1.f + __expf(-vz));
            float e = __expf(2.f * (vn + r * vh));
            float n = 1.f - 2.f / (e + 1.f);
            int hcol = hq + lr;
            float hold = bf2f(hin[(size_t)row * Hh + hcol]);
            hout[(size_t)row * Hh + hcol] = f2bf(n + z * (hold - n));
        }
}

// ---------------------------------------------------------------------------
// out = last @ out_w.T + out_b via MFMA. M=64, N=32000, K=256.
// ---------------------------------------------------------------------------
__global__ __launch_bounds__(256)
void k_out(const u16* __restrict__ h, const float* __restrict__ out_w,
           const float* __restrict__ out_b, float* __restrict__ out) {
    __shared__ u16 As[64 * 256];
    const int t = threadIdx.x;
    const int lane = t & 63, wid = t >> 6;
    const int colBlk = blockIdx.x * 128;
    const int wc = wid * 32;
    const int lr = lane & 15, hi = lane >> 4;

    #pragma unroll
    for (int i = 0; i < 8; ++i) {                   // 2048 chunks
        int c = t + i * 256;
        int r = c >> 5, kc = c & 31;
        bf16x8 v = *(const bf16x8*)(h + ((size_t)(r * Ss + (Ss - 1))) * Hh + kc * 8);
        ((bf16x8*)As)[r * 32 + (kc ^ (r & 7))] = v;
    }
    __syncthreads();

    f32x4 acc[4][2];
    #pragma unroll
    for (int a = 0; a < 4; ++a) { acc[a][0] = 0.0f; acc[a][1] = 0.0f; }

    #pragma unroll
    for (int ks = 0; ks < 8; ++ks) {
        bf16x8 af[4];
        #pragma unroll
        for (int f = 0; f < 4; ++f) {
            int ra = f * 16 + lr;
            af[f] = ((const bf16x8*)As)[ra * 32 + ((ks * 4 + hi) ^ (ra & 7))];
        }
        #pragma unroll
        for (int fn = 0; fn < 2; ++fn) {
            int n = colBlk + wc + fn * 16 + lr;
            const float* wp = out_w + (size_t)n * 256 + ks * 32 + hi * 8;
            float4 w0 = *(const float4*)wp, w1 = *(const float4*)(wp + 4);
            bf16x8 vb;
            vb[0]=(short)f2bf(w0.x); vb[1]=(short)f2bf(w0.y); vb[2]=(short)f2bf(w0.z); vb[3]=(short)f2bf(w0.w);
            vb[4]=(short)f2bf(w1.x); vb[5]=(short)f2bf(w1.y); vb[6]=(short)f2bf(w1.z); vb[7]=(short)f2bf(w1.w);
            #pragma unroll
            for (int fm = 0; fm < 4; ++fm)
                acc[fm][fn] = MFMA(af[fm], vb, acc[fm][fn]);
        }
    }
    #pragma unroll
    for (int fm = 0; fm < 4; ++fm)
        #pragma unroll
        for (int fn = 0; fn < 2; ++fn)
            #pragma unroll
            for (int i = 0; i < 4; ++i) {
                int row = fm * 16 + hi * 4 + i;
                int col = colBlk + wc + fn * 16 + lr;
                out[(size_t)row * Vv + col] = acc[fm][fn][i] + out_b[col];
            }
}

// ---------------------------------------------------------------------------
extern "C" void kernel_launch(void* const* d_in, const int* in_sizes, int n_in,
                              void* d_out, int out_size, void* d_ws, size_t ws_size,
                              hipStream_t stream) {
    const int*   x      = (const int*)  d_in[0];
    const float* emb    = (const float*)d_in[1];
    const float* W_edge = (const float*)d_in[2];
    const float* b_edge = (const float*)d_in[3];
    const float* W_ih   = (const float*)d_in[4];
    const float* W_hh   = (const float*)d_in[5];
    const float* b_ih   = (const float*)d_in[6];
    const float* b_hh   = (const float*)d_in[7];
    const float* out_w  = (const float*)d_in[8];
    const float* out_b  = (const float*)d_in[9];
    float* out = (float*)d_out;

    // ws: hA | hB | Bbig (bf16 1024x768) | bias (f32 3x1024)
    u16* hA   = (u16*)d_ws;
    u16* hB   = hA + (size_t)BS * Hh;
    u16* Bbig = hB + (size_t)BS * Hh;
    float* bias = (float*)(Bbig + (size_t)1024 * 768);

    k_prep_big <<<dim3(16, 9), 256, 0, stream>>>(W_edge, W_ih, W_hh, Bbig);
    k_prep_hn  <<<768, 256, 0, stream>>>(W_hh, Bbig);
    k_prep_bias<<<12, 256, 0, stream>>>(W_ih, b_edge, b_ih, b_hh, bias);
    k_embed    <<<BS * Hh / 8 / 256, 256, 0, stream>>>(x, emb, hA);

    u16* cur = hA;
    u16* nxt = hB;
    for (int step = 0; step < NSTEPS; ++step) {
        k_step<<<512, 512, 0, stream>>>(cur, Bbig, bias, nxt);
        u16* tmp = cur; cur = nxt; nxt = tmp;
    }
    k_out<<<Vv / 128, 256, 0, stream>>>(cur, out_w, out_b, out);
}